// Round 10
// baseline (167.399 us; speedup 1.0000x reference)
//
#include <hip/hip_runtime.h>
#include <hip/hip_bf16.h>

#define N 4096
#define D 128
#define TILE 128
#define NFF 4096.0f

typedef __attribute__((ext_vector_type(8))) short short8;
typedef __attribute__((ext_vector_type(4))) float f32x4;

#define LOG2E 1.44269504088896340736f
#define LN2   0.69314718055994530942f

#if __has_builtin(__builtin_amdgcn_rcpf)
__device__ __forceinline__ float fast_rcp(float x) { return __builtin_amdgcn_rcpf(x); }
#else
__device__ __forceinline__ float fast_rcp(float x) { return 1.f / x; }
#endif
#if __has_builtin(__builtin_amdgcn_logf)
__device__ __forceinline__ float fast_log2(float x) { return __builtin_amdgcn_logf(x); }
#else
__device__ __forceinline__ float fast_log2(float x) { return __log2f(x); }
#endif
#if __has_builtin(__builtin_amdgcn_exp2f)
__device__ __forceinline__ float fast_exp2(float x) { return __builtin_amdgcn_exp2f(x); }
#else
__device__ __forceinline__ float fast_exp2(float x) { return exp2f(x); }
#endif

__device__ __forceinline__ float sigx(float x) {   // sigmoid(x)
    return fast_rcp(1.f + fast_exp2(-x * LOG2E));
}

__device__ __forceinline__ unsigned short bf16_of(float v) {
    __hip_bfloat16 h = __float2bfloat16(v);
    return *reinterpret_cast<unsigned short*>(&h);
}

__device__ __forceinline__ float aload(const float* p) {
    return __hip_atomic_load(p, __ATOMIC_RELAXED, __HIP_MEMORY_SCOPE_AGENT);
}

// ---------------- kernel 0: cast to bf16 (float4), exact fp32 row norms, zero accumulators ----------------
// 512 blocks x 256 threads; 8 rows/block, 32 threads/row, 4 elems/thread
__global__ __launch_bounds__(256) void k_prep(
    const float* __restrict__ X, const float* __restrict__ Y,
    __hip_bfloat16* __restrict__ Xb, __hip_bfloat16* __restrict__ Yb,
    float* __restrict__ xn, float* __restrict__ yn,
    float* __restrict__ g4, int* __restrict__ syncv)
{
    const int tid = threadIdx.x, bid = blockIdx.x;
    const int row = bid * 8 + (tid >> 5);
    const int c4 = (tid & 31) * 4;
    const float4 vx = *(const float4*)&X[row * D + c4];
    const float4 vy = *(const float4*)&Y[row * D + c4];
    ushort4 hx, hy;
    hx.x = bf16_of(vx.x); hx.y = bf16_of(vx.y); hx.z = bf16_of(vx.z); hx.w = bf16_of(vx.w);
    hy.x = bf16_of(vy.x); hy.y = bf16_of(vy.y); hy.z = bf16_of(vy.z); hy.w = bf16_of(vy.w);
    *(ushort4*)&Xb[row * D + c4] = hx;
    *(ushort4*)&Yb[row * D + c4] = hy;
    float px = vx.x * vx.x + vx.y * vx.y + vx.z * vx.z + vx.w * vx.w;
    float py = vy.x * vy.x + vy.y * vy.y + vy.z * vy.z + vy.w * vy.w;
#pragma unroll
    for (int m = 1; m < 32; m <<= 1) { px += __shfl_xor(px, m); py += __shfl_xor(py, m); }
    if ((tid & 31) == 0) { xn[row] = px; yn[row] = py; }
    const int gid = bid * 256 + tid;
    if (gid < 4 * N) g4[gid] = 0.f;
    if (gid < 4) syncv[gid] = 0;
}

// ---------------- block reduction helper ----------------
__device__ __forceinline__ float block_sum(float v, float* sm)
{
#pragma unroll
    for (int m = 1; m < 64; m <<= 1) v += __shfl_xor(v, m);
    if ((threadIdx.x & 63) == 0) sm[threadIdx.x >> 6] = v;
    __syncthreads();
    float r = 0.f;
    if (threadIdx.x == 0) r = sm[0] + sm[1] + sm[2] + sm[3];
    __syncthreads();
    return r;  // valid on thread 0
}

// ---------------- main pass: MFMA + raw-e-moment epilogue + last-block finale ----------------
// acc[a][b][r]: j = col0 + wj + a*16 + quad*4 + r,  i = row0 + wi + b*16 + l16
// g4[v*N + i] = Σ_j e^(v+1),  e = 1/t = exp(L) exactly
__global__ __launch_bounds__(256) void k_main(
    const __hip_bfloat16* __restrict__ Yb, const __hip_bfloat16* __restrict__ Xb,
    const float* __restrict__ yn, const float* __restrict__ xn,
    float* __restrict__ pos, float* __restrict__ g4,
    int* __restrict__ syncv, float* __restrict__ out)
{
    __shared__ float rowAcc[4][TILE];
    __shared__ float sm[4];
    __shared__ float sLB;
    __shared__ int lastFlag;
    const int tid = threadIdx.x;
    const int bm = blockIdx.y, bn = blockIdx.x;
    const int row0 = bm * TILE, col0 = bn * TILE;   // row0 -> i (Y), col0 -> j (X)
    const int lane = tid & 63, wave = tid >> 6;
    const int wj = (wave >> 1) * 64, wi = (wave & 1) * 64;
    const int l16 = lane & 15, quad = lane >> 4;

    for (int v = tid; v < 4 * TILE; v += 256) (&rowAcc[0][0])[v] = 0.f;
    __syncthreads();

    f32x4 acc[4][4];
#pragma unroll
    for (int a = 0; a < 4; a++)
#pragma unroll
        for (int b = 0; b < 4; b++) acc[a][b] = f32x4{0.f, 0.f, 0.f, 0.f};

    const short8* Xg = (const short8*)(Xb + (size_t)col0 * D);   // j side (A)
    const short8* Yg = (const short8*)(Yb + (size_t)row0 * D);   // i side (B)

#pragma unroll
    for (int kk = 0; kk < 4; ++kk) {
        short8 af[4], bf[4];
#pragma unroll
        for (int t = 0; t < 4; t++) {
            af[t] = Xg[(wj + t * 16 + l16) * (D / 8) + kk * 4 + quad];
            bf[t] = Yg[(wi + t * 16 + l16) * (D / 8) + kk * 4 + quad];
        }
#pragma unroll
        for (int a = 0; a < 4; a++)
#pragma unroll
            for (int b = 0; b < 4; b++)
                acc[a][b] = __builtin_amdgcn_mfma_f32_16x16x32_bf16(af[a], bf[b], acc[a][b], 0, 0, 0);
    }

    float ynv[4];
#pragma unroll
    for (int b = 0; b < 4; b++) ynv[b] = yn[row0 + wi + b * 16 + l16];

    float o1[4] = {0.f, 0.f, 0.f, 0.f}, o2[4] = {0.f, 0.f, 0.f, 0.f};
    float o3[4] = {0.f, 0.f, 0.f, 0.f}, o4[4] = {0.f, 0.f, 0.f, 0.f};

#pragma unroll
    for (int a = 0; a < 4; a++) {
        const f32x4 xq = *(const f32x4*)&xn[col0 + wj + a * 16 + quad * 4];
        f32x4 x1;
#pragma unroll
        for (int r = 0; r < 4; r++) x1[r] = xq[r] + 1.f;
#pragma unroll
        for (int b = 0; b < 4; b++) {
#pragma unroll
            for (int r = 0; r < 4; r++) {
                float t = fmaxf(fmaf(-2.f, acc[a][b][r], ynv[b] + x1[r]), 1.f);
                float e = fast_rcp(t);       // e^L exactly
                float e2 = e * e;
                o1[b] += e;
                o2[b] += e2;
                o3[b] = fmaf(e, e2, o3[b]);
                o4[b] = fmaf(e2, e2, o4[b]);
            }
        }
    }

    // diagonal pos store (exact log), outside the hot loop; only 8 blocks take this path
    if (bm == bn && wi == wj && quad == (l16 >> 2)) {
        const int rr = l16 & 3;
#pragma unroll
        for (int b = 0; b < 4; b++) {
            float dacc;
#pragma unroll
            for (int r = 0; r < 4; r++) if (rr == r) dacc = acc[b][b][r];
            float t = fmaxf(fmaf(-2.f, dacc, ynv[b] + xn[col0 + wj + b * 16 + l16] + 1.f), 1.f);
            __hip_atomic_store(&pos[row0 + wi + b * 16 + l16], -LN2 * fast_log2(t),
                               __ATOMIC_RELAXED, __HIP_MEMORY_SCOPE_AGENT);
        }
    }

#pragma unroll
    for (int b = 0; b < 4; b++) {
        const int il = wi + b * 16 + l16;
        float v1 = o1[b], v2 = o2[b], v3 = o3[b], v4 = o4[b];
        v1 += __shfl_xor(v1, 16); v1 += __shfl_xor(v1, 32);
        v2 += __shfl_xor(v2, 16); v2 += __shfl_xor(v2, 32);
        v3 += __shfl_xor(v3, 16); v3 += __shfl_xor(v3, 32);
        v4 += __shfl_xor(v4, 16); v4 += __shfl_xor(v4, 32);
        if (lane < 16) {
            atomicAdd(&rowAcc[0][il], v1);
            atomicAdd(&rowAcc[1][il], v2);
            atomicAdd(&rowAcc[2][il], v3);
            atomicAdd(&rowAcc[3][il], v4);
        }
    }
    __syncthreads();
    for (int idx = tid; idx < 4 * TILE; idx += 256) {
        int v = idx >> 7, i = idx & 127;
        atomicAdd(&g4[v * N + row0 + i], rowAcc[v][i]);
    }

    // ---------------- last-block finale (replaces k_post dispatch) ----------------
    __threadfence();
    if (tid == 0) {
        int c = __hip_atomic_fetch_add(&syncv[0], 1, __ATOMIC_ACQ_REL, __HIP_MEMORY_SCOPE_AGENT);
        lastFlag = (c == 1023);
    }
    __syncthreads();
    if (!lastFlag) return;

    // ---- phase A: exact global reductions -> LB (one 256-thread block, 16 rows/thread) ----
    float aSpos = 0.f, aSneg = 0.f, aTL = 0.f, aSp = 0.f;
    for (int i = tid; i < N; i += 256) {
        float p  = aload(&pos[i]);
        float pe = fast_exp2(p * LOG2E);
        float E1 = aload(&g4[i]), E2 = aload(&g4[N + i]);
        float E3 = aload(&g4[2 * N + i]), E4 = aload(&g4[3 * N + i]);
        const float inN = 1.f / NFF;
        float m1 = E1 * inN, M2 = E2 * inN, M3 = E3 * inN, M4 = E4 * inN;
        float v2 = M2 - m1 * m1;
        float v3 = M3 - 3.f * m1 * M2 + 2.f * m1 * m1 * m1;
        float v4 = M4 - 4.f * m1 * M3 + 6.f * m1 * m1 * M2 - 3.f * m1 * m1 * m1 * m1;
        float im = fast_rcp(m1), im2 = im * im;
        float rowL = NFF * (LN2 * fast_log2(m1) - 0.5f * v2 * im2
                            + (1.f / 3.f) * v3 * im2 * im - 0.25f * v4 * im2 * im2);
        aSpos += pe; aSneg += E1 - pe; aTL += rowL - p; aSp += p;
    }
    float S_pos = block_sum(aSpos, sm);
    float S_neg = block_sum(aSneg, sm);
    float TLs   = block_sum(aTL, sm);
    float Sp    = block_sum(aSp, sm);
    if (tid == 0) {
        const float logM = __logf(NFF * (NFF - 1.f));
        float lb2 = __logf(S_neg) - logM;
        float lb1 = __logf(0.5f * ((NFF - 1.f) * S_pos + S_neg)) - logM;
        sLB = lb1 + lb2;
    }
    __syncthreads();
    const float LB = sLB;
    const float C2 = 2.f * fast_exp2(LB * LOG2E);

    // ---- phase B: e-space Taylor row sums + exact TP/diag corrections ----
    float aW = 0.f, aP = 0.f, aQ = 0.f, aTP = 0.f, aSG = 0.f;
    for (int i = tid; i < N; i += 256) {
        float p  = aload(&pos[i]);
        float pe = fast_exp2(p * LOG2E);
        float E1 = aload(&g4[i]), E2 = aload(&g4[N + i]);
        float E3 = aload(&g4[2 * N + i]), E4 = aload(&g4[3 * N + i]);
        const float inN = 1.f / NFF;
        float m1 = E1 * inN, M2 = E2 * inN, M3 = E3 * inN, M4 = E4 * inN;
        float v2 = M2 - m1 * m1;
        float v3 = M3 - 3.f * m1 * M2 + 2.f * m1 * m1 * m1;
        float v4 = M4 - 4.f * m1 * M3 + 6.f * m1 * m1 * M2 - 3.f * m1 * m1 * m1 * m1;

        float Roff = E1 - pe;
        float pf = p - LB + __logf(0.5f * ((NFF - 1.f) * pe + Roff)) - __logf(NFF - 1.f);
        aTP += sigx(pf);
        aSG += sigx(2.f * p - LB);

        // way: w(e) = ln(pe + e) - ln2
        float U = pe + m1;
        float r1 = fast_rcp(U), r12 = r1 * r1;
        aW += NFF * (LN2 * (fast_log2(U) - 1.f) - 0.5f * v2 * r12
                     + (1.f / 3.f) * v3 * r12 * r1 - 0.25f * v4 * r12 * r12);

        // P: F(e) = z/(z+C2), z = pe*(pe+e)
        float z0 = pe * U;
        float rp = fast_rcp(z0 + C2);
        float cp = C2 * rp * rp;
        float pe2 = pe * pe;
        aP += NFF * (z0 * rp - cp * rp * pe2 * v2
                     + cp * rp * rp * pe2 * pe * v3
                     - cp * rp * rp * rp * pe2 * pe2 * v4);

        // Q: G(e) = y/(y+C2), y = e*(pe+e)
        float y0 = m1 * U;
        float rq = fast_rcp(y0 + C2);
        float cq  = C2 * rq * rq;
        float Gy2 = -2.f * cq * rq;
        float Gy3 = 6.f * cq * rq * rq;
        float Gy4 = -24.f * cq * rq * rq * rq;
        float yp = pe + 2.f * m1, yp2 = yp * yp;
        float G2 = Gy2 * yp2 + 2.f * cq;
        float G3 = Gy3 * yp2 * yp + 6.f * Gy2 * yp;
        float G4 = Gy4 * yp2 * yp2 + 12.f * Gy3 * yp2 + 12.f * Gy2;
        aQ += NFF * (y0 * rq + 0.5f * G2 * v2 + (1.f / 6.f) * G3 * v3 + (1.f / 24.f) * G4 * v4);
    }
    float W   = block_sum(aW, sm);
    float P   = block_sum(aP, sm);
    float Q   = block_sum(aQ, sm);
    float tps = block_sum(aTP, sm);
    float sg  = block_sum(aSG, sm);
    if (tid == 0) {
        const float M = NFF * (NFF - 1.f);
        float Wo  = W - Sp;          // off-diagonal sum of way
        float SGP = P - sg;
        float SGN = Q - sg;
        float TP = tps * (1.f / NFF);
        float o0 = Sp / NFF + Wo / M - LB;
        float o1v = Wo / M + TLs / M - LB;
        float o2v = SGP / M, o3v = SGN / M;
        out[0] = o0;
        out[1] = o1v;
        out[2] = o2v;
        out[3] = o3v;
        out[4] = (TP + 1.f - o3v) * 0.5f;
        out[5] = TP;
        out[6] = TP / (TP + o3v);
        out[7] = LB;
        out[8] = -o0 + 2.0f;
    }
}

extern "C" void kernel_launch(void* const* d_in, const int* in_sizes, int n_in,
                              void* d_out, int out_size, void* d_ws, size_t ws_size,
                              hipStream_t stream)
{
    const float* X = (const float*)d_in[0];  // z_x (j / columns of logits)
    const float* Y = (const float*)d_in[1];  // z_y (i / rows of logits)
    float* out = (float*)d_out;

    char* ws = (char*)d_ws;
    __hip_bfloat16* Yb = (__hip_bfloat16*)(ws);
    __hip_bfloat16* Xb = (__hip_bfloat16*)(ws + (1 << 20));
    float* yn  = (float*)(ws + (2 << 20));
    float* xn  = yn + N;
    float* pos = xn + N;
    float* g4  = pos + N;          // 4*N per-row raw e-moments
    int*   syncv = (int*)(g4 + 4 * N);

    k_prep<<<512, 256, 0, stream>>>(X, Y, Xb, Yb, xn, yn, g4, syncv);
    k_main<<<dim3(N / TILE, N / TILE), 256, 0, stream>>>(Yb, Xb, yn, xn, pos, g4, syncv, out);
}

// Round 11
// 99.774 us; speedup vs baseline: 1.6778x; 1.6778x over previous
//
#include <hip/hip_runtime.h>
#include <hip/hip_bf16.h>

#define N 4096
#define D 128
#define TILE 128
#define NFF 4096.0f

typedef __attribute__((ext_vector_type(8))) short short8;
typedef __attribute__((ext_vector_type(4))) float f32x4;

#define LOG2E 1.44269504088896340736f
#define LN2   0.69314718055994530942f

#if __has_builtin(__builtin_amdgcn_rcpf)
__device__ __forceinline__ float fast_rcp(float x) { return __builtin_amdgcn_rcpf(x); }
#else
__device__ __forceinline__ float fast_rcp(float x) { return 1.f / x; }
#endif
#if __has_builtin(__builtin_amdgcn_logf)
__device__ __forceinline__ float fast_log2(float x) { return __builtin_amdgcn_logf(x); }
#else
__device__ __forceinline__ float fast_log2(float x) { return __log2f(x); }
#endif
#if __has_builtin(__builtin_amdgcn_exp2f)
__device__ __forceinline__ float fast_exp2(float x) { return __builtin_amdgcn_exp2f(x); }
#else
__device__ __forceinline__ float fast_exp2(float x) { return exp2f(x); }
#endif

__device__ __forceinline__ float sigx(float x) {   // sigmoid(x)
    return fast_rcp(1.f + fast_exp2(-x * LOG2E));
}

__device__ __forceinline__ unsigned short bf16_of(float v) {
    __hip_bfloat16 h = __float2bfloat16(v);
    return *reinterpret_cast<unsigned short*>(&h);
}

// ---------------- kernel 0: cast to bf16 (float4), exact fp32 row norms, zero accumulators ----------------
// 512 blocks x 256 threads; 8 rows/block, 32 threads/row, 4 elems/thread
__global__ __launch_bounds__(256) void k_prep(
    const float* __restrict__ X, const float* __restrict__ Y,
    __hip_bfloat16* __restrict__ Xb, __hip_bfloat16* __restrict__ Yb,
    float* __restrict__ xn, float* __restrict__ yn,
    float* __restrict__ g4, float* __restrict__ sc, int* __restrict__ syncv)
{
    const int tid = threadIdx.x, bid = blockIdx.x;
    const int row = bid * 8 + (tid >> 5);
    const int c4 = (tid & 31) * 4;
    const float4 vx = *(const float4*)&X[row * D + c4];
    const float4 vy = *(const float4*)&Y[row * D + c4];
    ushort4 hx, hy;
    hx.x = bf16_of(vx.x); hx.y = bf16_of(vx.y); hx.z = bf16_of(vx.z); hx.w = bf16_of(vx.w);
    hy.x = bf16_of(vy.x); hy.y = bf16_of(vy.y); hy.z = bf16_of(vy.z); hy.w = bf16_of(vy.w);
    *(ushort4*)&Xb[row * D + c4] = hx;
    *(ushort4*)&Yb[row * D + c4] = hy;
    float px = vx.x * vx.x + vx.y * vx.y + vx.z * vx.z + vx.w * vx.w;
    float py = vy.x * vy.x + vy.y * vy.y + vy.z * vy.z + vy.w * vy.w;
#pragma unroll
    for (int m = 1; m < 32; m <<= 1) { px += __shfl_xor(px, m); py += __shfl_xor(py, m); }
    if ((tid & 31) == 0) { xn[row] = px; yn[row] = py; }
    const int gid = bid * 256 + tid;
    if (gid < 4 * N) g4[gid] = 0.f;
    if (gid < 16) sc[gid] = 0.f;
    if (gid < 4) syncv[gid] = 0;
}

// ---------------- main pass: LDS-staging-free MFMA + raw-e-moment epilogue ----------------
// acc[a][b][r]: j = col0 + wj + a*16 + quad*4 + r,  i = row0 + wi + b*16 + l16
// Per-row outputs (g4[v*N + i]): v = Σ e^(v+1),  e = 1/t = exp(L) exactly
__global__ __launch_bounds__(256) void k_main(
    const __hip_bfloat16* __restrict__ Yb, const __hip_bfloat16* __restrict__ Xb,
    const float* __restrict__ yn, const float* __restrict__ xn,
    float* __restrict__ pos, float* __restrict__ g4)
{
    __shared__ float rowAcc[4][TILE];
    const int tid = threadIdx.x;
    const int bm = blockIdx.y, bn = blockIdx.x;
    const int row0 = bm * TILE, col0 = bn * TILE;   // row0 -> i (Y), col0 -> j (X)
    const int lane = tid & 63, wave = tid >> 6;
    const int wj = (wave >> 1) * 64, wi = (wave & 1) * 64;
    const int l16 = lane & 15, quad = lane >> 4;

    for (int v = tid; v < 4 * TILE; v += 256) (&rowAcc[0][0])[v] = 0.f;
    __syncthreads();

    f32x4 acc[4][4];
#pragma unroll
    for (int a = 0; a < 4; a++)
#pragma unroll
        for (int b = 0; b < 4; b++) acc[a][b] = f32x4{0.f, 0.f, 0.f, 0.f};

    const short8* Xg = (const short8*)(Xb + (size_t)col0 * D);   // j side (A)
    const short8* Yg = (const short8*)(Yb + (size_t)row0 * D);   // i side (B)

#pragma unroll
    for (int kk = 0; kk < 4; ++kk) {
        short8 af[4], bf[4];
#pragma unroll
        for (int t = 0; t < 4; t++) {
            af[t] = Xg[(wj + t * 16 + l16) * (D / 8) + kk * 4 + quad];
            bf[t] = Yg[(wi + t * 16 + l16) * (D / 8) + kk * 4 + quad];
        }
#pragma unroll
        for (int a = 0; a < 4; a++)
#pragma unroll
            for (int b = 0; b < 4; b++)
                acc[a][b] = __builtin_amdgcn_mfma_f32_16x16x32_bf16(af[a], bf[b], acc[a][b], 0, 0, 0);
    }

    float ynv[4];
#pragma unroll
    for (int b = 0; b < 4; b++) ynv[b] = yn[row0 + wi + b * 16 + l16];

    float o1[4] = {0.f, 0.f, 0.f, 0.f}, o2[4] = {0.f, 0.f, 0.f, 0.f};
    float o3[4] = {0.f, 0.f, 0.f, 0.f}, o4[4] = {0.f, 0.f, 0.f, 0.f};

#pragma unroll
    for (int a = 0; a < 4; a++) {
        const f32x4 xq = *(const f32x4*)&xn[col0 + wj + a * 16 + quad * 4];
        f32x4 x1;
#pragma unroll
        for (int r = 0; r < 4; r++) x1[r] = xq[r] + 1.f;
#pragma unroll
        for (int b = 0; b < 4; b++) {
#pragma unroll
            for (int r = 0; r < 4; r++) {
                float t = fmaxf(fmaf(-2.f, acc[a][b][r], ynv[b] + x1[r]), 1.f);
                float e = fast_rcp(t);       // e^L exactly
                float e2 = e * e;
                o1[b] += e;
                o2[b] += e2;
                o3[b] = fmaf(e, e2, o3[b]);
                o4[b] = fmaf(e2, e2, o4[b]);
            }
        }
    }

    // diagonal pos store (exact log), outside the hot loop; only 8 blocks take this path
    if (bm == bn && wi == wj && quad == (l16 >> 2)) {
        const int rr = l16 & 3;
#pragma unroll
        for (int b = 0; b < 4; b++) {
            float dacc;
#pragma unroll
            for (int r = 0; r < 4; r++) if (rr == r) dacc = acc[b][b][r];
            float t = fmaxf(fmaf(-2.f, dacc, ynv[b] + xn[col0 + wj + b * 16 + l16] + 1.f), 1.f);
            pos[row0 + wi + b * 16 + l16] = -LN2 * fast_log2(t);
        }
    }

#pragma unroll
    for (int b = 0; b < 4; b++) {
        const int il = wi + b * 16 + l16;
        float v1 = o1[b], v2 = o2[b], v3 = o3[b], v4 = o4[b];
        v1 += __shfl_xor(v1, 16); v1 += __shfl_xor(v1, 32);
        v2 += __shfl_xor(v2, 16); v2 += __shfl_xor(v2, 32);
        v3 += __shfl_xor(v3, 16); v3 += __shfl_xor(v3, 32);
        v4 += __shfl_xor(v4, 16); v4 += __shfl_xor(v4, 32);
        if (lane < 16) {
            atomicAdd(&rowAcc[0][il], v1);
            atomicAdd(&rowAcc[1][il], v2);
            atomicAdd(&rowAcc[2][il], v3);
            atomicAdd(&rowAcc[3][il], v4);
        }
    }
    __syncthreads();
    for (int idx = tid; idx < 4 * TILE; idx += 256) {
        int v = idx >> 7, i = idx & 127;
        atomicAdd(&g4[v * N + row0 + i], rowAcc[v][i]);
    }
}

// ---------------- block reduction helper ----------------
__device__ __forceinline__ float block_sum(float v, float* sm)
{
#pragma unroll
    for (int m = 1; m < 64; m <<= 1) v += __shfl_xor(v, m);
    if ((threadIdx.x & 63) == 0) sm[threadIdx.x >> 6] = v;
    __syncthreads();
    float r = 0.f;
    if (threadIdx.x == 0) r = sm[0] + sm[1] + sm[2] + sm[3];
    __syncthreads();
    return r;  // valid on thread 0
}

// ---------------- k_post: LB (exact) + e-space-moment W/P/Q + outputs. 32 blocks, 8 rows/thread ----------------
__global__ __launch_bounds__(256) void k_post(
    const float* __restrict__ pos, const float* __restrict__ g4,
    float* __restrict__ sc, int* __restrict__ syncv, float* __restrict__ out)
{
    __shared__ float sm[4];
    __shared__ float sLB;
    const int tid = threadIdx.x;
    const int nb = gridDim.x;
    const int base = blockIdx.x * 256 + tid;   // rows: base + k*8192, k=0..? (nb*256 stride over N)
    const int stride = nb * 256;

    // ---- per-thread row accumulation for phase A ----
    float aSpos = 0.f, aSneg = 0.f, aTL = 0.f, aSp = 0.f;
#pragma unroll 4
    for (int i = base; i < N; i += stride) {
        float p  = pos[i];
        float pe = fast_exp2(p * LOG2E);
        float E1 = g4[i], E2 = g4[N + i], E3 = g4[2 * N + i], E4 = g4[3 * N + i];
        const float inN = 1.f / NFF;
        float m1 = E1 * inN, M2 = E2 * inN, M3 = E3 * inN, M4 = E4 * inN;
        float v2 = M2 - m1 * m1;
        float v3 = M3 - 3.f * m1 * M2 + 2.f * m1 * m1 * m1;
        float v4 = M4 - 4.f * m1 * M3 + 6.f * m1 * m1 * M2 - 3.f * m1 * m1 * m1 * m1;
        float im = fast_rcp(m1), im2 = im * im;
        float rowL = NFF * (LN2 * fast_log2(m1) - 0.5f * v2 * im2
                            + (1.f / 3.f) * v3 * im2 * im - 0.25f * v4 * im2 * im2);
        aSpos += pe; aSneg += E1 - pe; aTL += rowL - p; aSp += p;
    }
    float bs;
    bs = block_sum(aSpos, sm);  if (tid == 0) atomicAdd(&sc[10], bs);
    bs = block_sum(aSneg, sm);  if (tid == 0) atomicAdd(&sc[11], bs);
    bs = block_sum(aTL, sm);    if (tid == 0) atomicAdd(&sc[12], bs);
    bs = block_sum(aSp, sm);    if (tid == 0) atomicAdd(&sc[13], bs);
    __threadfence();
    if (tid == 0) {
        int c = __hip_atomic_fetch_add(&syncv[0], 1, __ATOMIC_ACQ_REL, __HIP_MEMORY_SCOPE_AGENT);
        if (c == nb - 1) {
            float S_pos = __hip_atomic_load(&sc[10], __ATOMIC_RELAXED, __HIP_MEMORY_SCOPE_AGENT);
            float S_neg = __hip_atomic_load(&sc[11], __ATOMIC_RELAXED, __HIP_MEMORY_SCOPE_AGENT);
            float TLs   = __hip_atomic_load(&sc[12], __ATOMIC_RELAXED, __HIP_MEMORY_SCOPE_AGENT);
            float Sp    = __hip_atomic_load(&sc[13], __ATOMIC_RELAXED, __HIP_MEMORY_SCOPE_AGENT);
            const float logM = __logf(NFF * (NFF - 1.f));
            float lb2 = __logf(S_neg) - logM;
            float lb1 = __logf(0.5f * ((NFF - 1.f) * S_pos + S_neg)) - logM;
            float LB = lb1 + lb2;
            __hip_atomic_store(&sc[3], LB,  __ATOMIC_RELAXED, __HIP_MEMORY_SCOPE_AGENT);
            __hip_atomic_store(&sc[4], Sp,  __ATOMIC_RELAXED, __HIP_MEMORY_SCOPE_AGENT);
            __hip_atomic_store(&sc[5], TLs, __ATOMIC_RELAXED, __HIP_MEMORY_SCOPE_AGENT);
            __hip_atomic_store(&syncv[1], 1, __ATOMIC_RELEASE, __HIP_MEMORY_SCOPE_AGENT);
        }
        while (__hip_atomic_load(&syncv[1], __ATOMIC_ACQUIRE, __HIP_MEMORY_SCOPE_AGENT) == 0)
            __builtin_amdgcn_s_sleep(8);
        sLB = __hip_atomic_load(&sc[3], __ATOMIC_RELAXED, __HIP_MEMORY_SCOPE_AGENT);
    }
    __syncthreads();
    const float LB = sLB;
    const float C2 = 2.f * fast_exp2(LB * LOG2E);

    // ---- phase B: e-space Taylor row sums + exact TP/diag corrections ----
    float aW = 0.f, aP = 0.f, aQ = 0.f, aTP = 0.f, aSG = 0.f;
#pragma unroll 4
    for (int i = base; i < N; i += stride) {
        float p  = pos[i];
        float pe = fast_exp2(p * LOG2E);
        float E1 = g4[i], E2 = g4[N + i], E3 = g4[2 * N + i], E4 = g4[3 * N + i];
        const float inN = 1.f / NFF;
        float m1 = E1 * inN, M2 = E2 * inN, M3 = E3 * inN, M4 = E4 * inN;
        float v2 = M2 - m1 * m1;
        float v3 = M3 - 3.f * m1 * M2 + 2.f * m1 * m1 * m1;
        float v4 = M4 - 4.f * m1 * M3 + 6.f * m1 * m1 * M2 - 3.f * m1 * m1 * m1 * m1;

        float Roff = E1 - pe;
        float pf = p - LB + __logf(0.5f * ((NFF - 1.f) * pe + Roff)) - __logf(NFF - 1.f);
        aTP += sigx(pf);
        aSG += sigx(2.f * p - LB);

        // way: w(e) = ln(pe + e) - ln2
        float U = pe + m1;
        float r1 = fast_rcp(U), r12 = r1 * r1;
        aW += NFF * (LN2 * (fast_log2(U) - 1.f) - 0.5f * v2 * r12
                     + (1.f / 3.f) * v3 * r12 * r1 - 0.25f * v4 * r12 * r12);

        // P: F(e) = z/(z+C2), z = pe*(pe+e)
        float z0 = pe * U;
        float rp = fast_rcp(z0 + C2);
        float cp = C2 * rp * rp;
        float pe2 = pe * pe;
        aP += NFF * (z0 * rp - cp * rp * pe2 * v2
                     + cp * rp * rp * pe2 * pe * v3
                     - cp * rp * rp * rp * pe2 * pe2 * v4);

        // Q: G(e) = y/(y+C2), y = e*(pe+e)
        float y0 = m1 * U;
        float rq = fast_rcp(y0 + C2);
        float cq  = C2 * rq * rq;
        float Gy2 = -2.f * cq * rq;
        float Gy3 = 6.f * cq * rq * rq;
        float Gy4 = -24.f * cq * rq * rq * rq;
        float yp = pe + 2.f * m1, yp2 = yp * yp;
        float G2 = Gy2 * yp2 + 2.f * cq;
        float G3 = Gy3 * yp2 * yp + 6.f * Gy2 * yp;
        float G4 = Gy4 * yp2 * yp2 + 12.f * Gy3 * yp2 + 12.f * Gy2;
        aQ += NFF * (y0 * rq + 0.5f * G2 * v2 + (1.f / 6.f) * G3 * v3 + (1.f / 24.f) * G4 * v4);
    }
    bs = block_sum(aW, sm);   if (tid == 0) atomicAdd(&sc[0], bs);
    bs = block_sum(aP, sm);   if (tid == 0) atomicAdd(&sc[1], bs);
    bs = block_sum(aQ, sm);   if (tid == 0) atomicAdd(&sc[2], bs);
    bs = block_sum(aTP, sm);  if (tid == 0) atomicAdd(&sc[6], bs);
    bs = block_sum(aSG, sm);  if (tid == 0) atomicAdd(&sc[7], bs);
    __threadfence();
    if (tid == 0) {
        int c = __hip_atomic_fetch_add(&syncv[2], 1, __ATOMIC_ACQ_REL, __HIP_MEMORY_SCOPE_AGENT);
        if (c == nb - 1) {
            float W   = __hip_atomic_load(&sc[0], __ATOMIC_RELAXED, __HIP_MEMORY_SCOPE_AGENT);
            float P   = __hip_atomic_load(&sc[1], __ATOMIC_RELAXED, __HIP_MEMORY_SCOPE_AGENT);
            float Q   = __hip_atomic_load(&sc[2], __ATOMIC_RELAXED, __HIP_MEMORY_SCOPE_AGENT);
            float tps = __hip_atomic_load(&sc[6], __ATOMIC_RELAXED, __HIP_MEMORY_SCOPE_AGENT);
            float sg  = __hip_atomic_load(&sc[7], __ATOMIC_RELAXED, __HIP_MEMORY_SCOPE_AGENT);
            float Sp  = __hip_atomic_load(&sc[4], __ATOMIC_RELAXED, __HIP_MEMORY_SCOPE_AGENT);
            float TLs = __hip_atomic_load(&sc[5], __ATOMIC_RELAXED, __HIP_MEMORY_SCOPE_AGENT);
            const float M = NFF * (NFF - 1.f);
            float Wo  = W - Sp;          // off-diagonal sum of way
            float SGP = P - sg;
            float SGN = Q - sg;
            float TP = tps * (1.f / NFF);
            float o0 = Sp / NFF + Wo / M - LB;
            float o1 = Wo / M + TLs / M - LB;
            float o2 = SGP / M, o3 = SGN / M;
            out[0] = o0;
            out[1] = o1;
            out[2] = o2;
            out[3] = o3;
            out[4] = (TP + 1.f - o3) * 0.5f;
            out[5] = TP;
            out[6] = TP / (TP + o3);
            out[7] = LB;
            out[8] = -o0 + 2.0f;
        }
    }
}

extern "C" void kernel_launch(void* const* d_in, const int* in_sizes, int n_in,
                              void* d_out, int out_size, void* d_ws, size_t ws_size,
                              hipStream_t stream)
{
    const float* X = (const float*)d_in[0];  // z_x (j / columns of logits)
    const float* Y = (const float*)d_in[1];  // z_y (i / rows of logits)
    float* out = (float*)d_out;

    char* ws = (char*)d_ws;
    __hip_bfloat16* Yb = (__hip_bfloat16*)(ws);
    __hip_bfloat16* Xb = (__hip_bfloat16*)(ws + (1 << 20));
    float* yn  = (float*)(ws + (2 << 20));
    float* xn  = yn + N;
    float* pos = xn + N;
    float* g4  = pos + N;          // 4*N per-row raw e-moments
    float* sc  = g4 + 4 * N;       // 16 scalars
    int*   syncv = (int*)(sc + 16);

    k_prep<<<512, 256, 0, stream>>>(X, Y, Xb, Yb, xn, yn, g4, sc, syncv);
    k_main<<<dim3(N / TILE, N / TILE), 256, 0, stream>>>(Yb, Xb, yn, xn, pos, g4);
    k_post<<<32, 256, 0, stream>>>(pos, g4, sc, syncv, out);
}

// Round 12
// 96.896 us; speedup vs baseline: 1.7276x; 1.0297x over previous
//
#include <hip/hip_runtime.h>
#include <hip/hip_bf16.h>

#define N 4096
#define D 128
#define TILE 128
#define NFF 4096.0f

typedef __attribute__((ext_vector_type(8))) short short8;
typedef __attribute__((ext_vector_type(4))) float f32x4;

#define LOG2E 1.44269504088896340736f
#define LN2   0.69314718055994530942f

#if __has_builtin(__builtin_amdgcn_rcpf)
__device__ __forceinline__ float fast_rcp(float x) { return __builtin_amdgcn_rcpf(x); }
#else
__device__ __forceinline__ float fast_rcp(float x) { return 1.f / x; }
#endif
#if __has_builtin(__builtin_amdgcn_logf)
__device__ __forceinline__ float fast_log2(float x) { return __builtin_amdgcn_logf(x); }
#else
__device__ __forceinline__ float fast_log2(float x) { return __log2f(x); }
#endif
#if __has_builtin(__builtin_amdgcn_exp2f)
__device__ __forceinline__ float fast_exp2(float x) { return __builtin_amdgcn_exp2f(x); }
#else
__device__ __forceinline__ float fast_exp2(float x) { return exp2f(x); }
#endif

__device__ __forceinline__ float sigx(float x) {   // sigmoid(x)
    return fast_rcp(1.f + fast_exp2(-x * LOG2E));
}

__device__ __forceinline__ unsigned short bf16_of(float v) {
    __hip_bfloat16 h = __float2bfloat16(v);
    return *reinterpret_cast<unsigned short*>(&h);
}

// ---------------- kernel 0: cast to bf16 (float4), exact fp32 row norms, zero accumulators ----------------
// 512 blocks x 256 threads; 8 rows/block, 32 threads/row, 4 elems/thread
__global__ __launch_bounds__(256) void k_prep(
    const float* __restrict__ X, const float* __restrict__ Y,
    __hip_bfloat16* __restrict__ Xb, __hip_bfloat16* __restrict__ Yb,
    float* __restrict__ xn, float* __restrict__ yn,
    float* __restrict__ g4, float* __restrict__ sc, int* __restrict__ syncv)
{
    const int tid = threadIdx.x, bid = blockIdx.x;
    const int row = bid * 8 + (tid >> 5);
    const int c4 = (tid & 31) * 4;
    const float4 vx = *(const float4*)&X[row * D + c4];
    const float4 vy = *(const float4*)&Y[row * D + c4];
    ushort4 hx, hy;
    hx.x = bf16_of(vx.x); hx.y = bf16_of(vx.y); hx.z = bf16_of(vx.z); hx.w = bf16_of(vx.w);
    hy.x = bf16_of(vy.x); hy.y = bf16_of(vy.y); hy.z = bf16_of(vy.z); hy.w = bf16_of(vy.w);
    *(ushort4*)&Xb[row * D + c4] = hx;
    *(ushort4*)&Yb[row * D + c4] = hy;
    float px = vx.x * vx.x + vx.y * vx.y + vx.z * vx.z + vx.w * vx.w;
    float py = vy.x * vy.x + vy.y * vy.y + vy.z * vy.z + vy.w * vy.w;
#pragma unroll
    for (int m = 1; m < 32; m <<= 1) { px += __shfl_xor(px, m); py += __shfl_xor(py, m); }
    if ((tid & 31) == 0) { xn[row] = px; yn[row] = py; }
    const int gid = bid * 256 + tid;
    if (gid < 4 * N) g4[gid] = 0.f;
    if (gid < 16) sc[gid] = 0.f;
    if (gid < 4) syncv[gid] = 0;
}

// ---------------- main pass: LDS-staging-free MFMA + raw-e-moment epilogue ----------------
// acc[a][b][r]: j = col0 + wj + a*16 + quad*4 + r,  i = row0 + wi + b*16 + l16
// Per-row outputs (g4[v*N + i]): v = Σ e^(v+1),  e = 1/t = exp(L) exactly
__global__ __launch_bounds__(256) void k_main(
    const __hip_bfloat16* __restrict__ Yb, const __hip_bfloat16* __restrict__ Xb,
    const float* __restrict__ yn, const float* __restrict__ xn,
    float* __restrict__ pos, float* __restrict__ g4)
{
    __shared__ float rowAcc[4][TILE];
    const int tid = threadIdx.x;
    const int bm = blockIdx.y, bn = blockIdx.x;
    const int row0 = bm * TILE, col0 = bn * TILE;   // row0 -> i (Y), col0 -> j (X)
    const int lane = tid & 63, wave = tid >> 6;
    const int wj = (wave >> 1) * 64, wi = (wave & 1) * 64;
    const int l16 = lane & 15, quad = lane >> 4;

    for (int v = tid; v < 4 * TILE; v += 256) (&rowAcc[0][0])[v] = 0.f;
    __syncthreads();

    f32x4 acc[4][4];
#pragma unroll
    for (int a = 0; a < 4; a++)
#pragma unroll
        for (int b = 0; b < 4; b++) acc[a][b] = f32x4{0.f, 0.f, 0.f, 0.f};

    const short8* Xg = (const short8*)(Xb + (size_t)col0 * D);   // j side (A)
    const short8* Yg = (const short8*)(Yb + (size_t)row0 * D);   // i side (B)

#pragma unroll
    for (int kk = 0; kk < 4; ++kk) {
        short8 af[4], bf[4];
#pragma unroll
        for (int t = 0; t < 4; t++) {
            af[t] = Xg[(wj + t * 16 + l16) * (D / 8) + kk * 4 + quad];
            bf[t] = Yg[(wi + t * 16 + l16) * (D / 8) + kk * 4 + quad];
        }
#pragma unroll
        for (int a = 0; a < 4; a++)
#pragma unroll
            for (int b = 0; b < 4; b++)
                acc[a][b] = __builtin_amdgcn_mfma_f32_16x16x32_bf16(af[a], bf[b], acc[a][b], 0, 0, 0);
    }

    float ynv[4];
#pragma unroll
    for (int b = 0; b < 4; b++) ynv[b] = yn[row0 + wi + b * 16 + l16];

    float o1[4] = {0.f, 0.f, 0.f, 0.f}, o2[4] = {0.f, 0.f, 0.f, 0.f};
    float o3[4] = {0.f, 0.f, 0.f, 0.f}, o4[4] = {0.f, 0.f, 0.f, 0.f};

#pragma unroll
    for (int a = 0; a < 4; a++) {
        const f32x4 xq = *(const f32x4*)&xn[col0 + wj + a * 16 + quad * 4];
        f32x4 x1;
#pragma unroll
        for (int r = 0; r < 4; r++) x1[r] = xq[r] + 1.f;
#pragma unroll
        for (int b = 0; b < 4; b++) {
#pragma unroll
            for (int r = 0; r < 4; r++) {
                float t = fmaxf(fmaf(-2.f, acc[a][b][r], ynv[b] + x1[r]), 1.f);
                float e = fast_rcp(t);       // e^L exactly
                float e2 = e * e;
                o1[b] += e;
                o2[b] += e2;
                o3[b] = fmaf(e, e2, o3[b]);
                o4[b] = fmaf(e2, e2, o4[b]);
            }
        }
    }

    // diagonal pos store (exact log), outside the hot loop; only 8 blocks take this path
    if (bm == bn && wi == wj && quad == (l16 >> 2)) {
        const int rr = l16 & 3;
#pragma unroll
        for (int b = 0; b < 4; b++) {
            float dacc;
#pragma unroll
            for (int r = 0; r < 4; r++) if (rr == r) dacc = acc[b][b][r];
            float t = fmaxf(fmaf(-2.f, dacc, ynv[b] + xn[col0 + wj + b * 16 + l16] + 1.f), 1.f);
            pos[row0 + wi + b * 16 + l16] = -LN2 * fast_log2(t);
        }
    }

#pragma unroll
    for (int b = 0; b < 4; b++) {
        const int il = wi + b * 16 + l16;
        float v1 = o1[b], v2 = o2[b], v3 = o3[b], v4 = o4[b];
        v1 += __shfl_xor(v1, 16); v1 += __shfl_xor(v1, 32);
        v2 += __shfl_xor(v2, 16); v2 += __shfl_xor(v2, 32);
        v3 += __shfl_xor(v3, 16); v3 += __shfl_xor(v3, 32);
        v4 += __shfl_xor(v4, 16); v4 += __shfl_xor(v4, 32);
        if (lane < 16) {
            atomicAdd(&rowAcc[0][il], v1);
            atomicAdd(&rowAcc[1][il], v2);
            atomicAdd(&rowAcc[2][il], v3);
            atomicAdd(&rowAcc[3][il], v4);
        }
    }
    __syncthreads();
    for (int idx = tid; idx < 4 * TILE; idx += 256) {
        int v = idx >> 7, i = idx & 127;
        atomicAdd(&g4[v * N + row0 + i], rowAcc[v][i]);
    }
}

// ---------------- block reduction helper ----------------
__device__ __forceinline__ float block_sum(float v, float* sm)
{
#pragma unroll
    for (int m = 1; m < 64; m <<= 1) v += __shfl_xor(v, m);
    if ((threadIdx.x & 63) == 0) sm[threadIdx.x >> 6] = v;
    __syncthreads();
    float r = 0.f;
    if (threadIdx.x == 0) r = sm[0] + sm[1] + sm[2] + sm[3];
    __syncthreads();
    return r;  // valid on thread 0
}

// ---------------- k_post: LB (exact) + e-space-moment W/P/Q + outputs. 16 blocks, 1 row/thread ----------------
__global__ __launch_bounds__(256) void k_post(
    const float* __restrict__ pos, const float* __restrict__ g4,
    float* __restrict__ sc, int* __restrict__ syncv, float* __restrict__ out)
{
    __shared__ float sm[4];
    __shared__ float sLB;
    const int tid = threadIdx.x;
    const int i = blockIdx.x * 256 + tid;
    const int nb = gridDim.x;

    const float p  = pos[i];
    const float pe = fast_exp2(p * LOG2E);
    const float E1 = g4[i], E2 = g4[N + i], E3 = g4[2 * N + i], E4 = g4[3 * N + i];

    // central moments of e over the row (diag included; exact-diag corrections applied later)
    const float inN = 1.f / NFF;
    const float m1 = E1 * inN;
    const float M2 = E2 * inN, M3 = E3 * inN, M4 = E4 * inN;
    const float v2 = M2 - m1 * m1;
    const float v3 = M3 - 3.f * m1 * M2 + 2.f * m1 * m1 * m1;
    const float v4 = M4 - 4.f * m1 * M3 + 6.f * m1 * m1 * M2 - 3.f * m1 * m1 * m1 * m1;

    // Sum_j ln e_j via log-series around m1
    const float im = fast_rcp(m1), im2 = im * im;
    const float rowL = NFF * (LN2 * fast_log2(m1) - 0.5f * v2 * im2
                              + (1.f / 3.f) * v3 * im2 * im - 0.25f * v4 * im2 * im2);

    // ---- phase A: exact global reductions -> LB ----
    float bs;
    bs = block_sum(pe, sm);         if (tid == 0) atomicAdd(&sc[10], bs);
    bs = block_sum(E1 - pe, sm);    if (tid == 0) atomicAdd(&sc[11], bs);
    bs = block_sum(rowL - p, sm);   if (tid == 0) atomicAdd(&sc[12], bs);
    bs = block_sum(p, sm);          if (tid == 0) atomicAdd(&sc[13], bs);
    __threadfence();
    if (tid == 0) {
        int c = __hip_atomic_fetch_add(&syncv[0], 1, __ATOMIC_ACQ_REL, __HIP_MEMORY_SCOPE_AGENT);
        if (c == nb - 1) {
            float S_pos = __hip_atomic_load(&sc[10], __ATOMIC_RELAXED, __HIP_MEMORY_SCOPE_AGENT);
            float S_neg = __hip_atomic_load(&sc[11], __ATOMIC_RELAXED, __HIP_MEMORY_SCOPE_AGENT);
            float TLs   = __hip_atomic_load(&sc[12], __ATOMIC_RELAXED, __HIP_MEMORY_SCOPE_AGENT);
            float Sp    = __hip_atomic_load(&sc[13], __ATOMIC_RELAXED, __HIP_MEMORY_SCOPE_AGENT);
            const float logM = __logf(NFF * (NFF - 1.f));
            float lb2 = __logf(S_neg) - logM;
            float lb1 = __logf(0.5f * ((NFF - 1.f) * S_pos + S_neg)) - logM;
            float LB = lb1 + lb2;
            __hip_atomic_store(&sc[3], LB,  __ATOMIC_RELAXED, __HIP_MEMORY_SCOPE_AGENT);
            __hip_atomic_store(&sc[4], Sp,  __ATOMIC_RELAXED, __HIP_MEMORY_SCOPE_AGENT);
            __hip_atomic_store(&sc[5], TLs, __ATOMIC_RELAXED, __HIP_MEMORY_SCOPE_AGENT);
            __hip_atomic_store(&syncv[1], 1, __ATOMIC_RELEASE, __HIP_MEMORY_SCOPE_AGENT);
        }
        while (__hip_atomic_load(&syncv[1], __ATOMIC_ACQUIRE, __HIP_MEMORY_SCOPE_AGENT) == 0)
            __builtin_amdgcn_s_sleep(8);
        sLB = __hip_atomic_load(&sc[3], __ATOMIC_RELAXED, __HIP_MEMORY_SCOPE_AGENT);
    }
    __syncthreads();
    const float LB = sLB;
    const float C2 = 2.f * fast_exp2(LB * LOG2E);

    // ---- exact per-row: TP term and diag sigmoid correction ----
    float Roff = E1 - pe;
    float pf = p - LB + __logf(0.5f * ((NFF - 1.f) * pe + Roff)) - __logf(NFF - 1.f);
    float tp  = sigx(pf);
    float sgd = sigx(2.f * p - LB);

    // ---- e-space Taylor row sums ----
    // way: w(e) = ln(pe + e) - ln2
    const float U = pe + m1;
    const float r1 = fast_rcp(U), r12 = r1 * r1;
    float Wi = NFF * (LN2 * (fast_log2(U) - 1.f) - 0.5f * v2 * r12
                      + (1.f / 3.f) * v3 * r12 * r1 - 0.25f * v4 * r12 * r12);

    // P: F(e) = z/(z+C2), z = pe*(pe+e)  [= sigmoid(pos+way-LB)]
    const float z0 = pe * U;
    const float rp = fast_rcp(z0 + C2);
    const float cp = C2 * rp * rp;      // F' / pe
    const float pe2 = pe * pe;
    float Pi = NFF * (z0 * rp - cp * rp * pe2 * v2
                      + cp * rp * rp * pe2 * pe * v3
                      - cp * rp * rp * rp * pe2 * pe2 * v4);

    // Q: G(e) = y/(y+C2), y = e*(pe+e)  [= sigmoid(way+L-LB)]
    const float y0 = m1 * U;
    const float rq = fast_rcp(y0 + C2);
    const float cq  = C2 * rq * rq;             // dG/dy
    const float Gy2 = -2.f * cq * rq;           // d2G/dy2
    const float Gy3 = 6.f * cq * rq * rq;       // d3G/dy3
    const float Gy4 = -24.f * cq * rq * rq * rq;
    const float yp = pe + 2.f * m1;             // dy/de (d2y/de2 = 2)
    const float yp2 = yp * yp;
    float G2 = Gy2 * yp2 + 2.f * cq;
    float G3 = Gy3 * yp2 * yp + 6.f * Gy2 * yp;
    float G4 = Gy4 * yp2 * yp2 + 12.f * Gy3 * yp2 + 12.f * Gy2;
    float Qi = NFF * (y0 * rq + 0.5f * G2 * v2 + (1.f / 6.f) * G3 * v3 + (1.f / 24.f) * G4 * v4);

    bs = block_sum(Wi, sm);  if (tid == 0) atomicAdd(&sc[0], bs);
    bs = block_sum(Pi, sm);  if (tid == 0) atomicAdd(&sc[1], bs);
    bs = block_sum(Qi, sm);  if (tid == 0) atomicAdd(&sc[2], bs);
    bs = block_sum(tp, sm);  if (tid == 0) atomicAdd(&sc[6], bs);
    bs = block_sum(sgd, sm); if (tid == 0) atomicAdd(&sc[7], bs);
    __threadfence();
    if (tid == 0) {
        int c = __hip_atomic_fetch_add(&syncv[2], 1, __ATOMIC_ACQ_REL, __HIP_MEMORY_SCOPE_AGENT);
        if (c == nb - 1) {
            float W   = __hip_atomic_load(&sc[0], __ATOMIC_RELAXED, __HIP_MEMORY_SCOPE_AGENT);
            float P   = __hip_atomic_load(&sc[1], __ATOMIC_RELAXED, __HIP_MEMORY_SCOPE_AGENT);
            float Q   = __hip_atomic_load(&sc[2], __ATOMIC_RELAXED, __HIP_MEMORY_SCOPE_AGENT);
            float tps = __hip_atomic_load(&sc[6], __ATOMIC_RELAXED, __HIP_MEMORY_SCOPE_AGENT);
            float sg  = __hip_atomic_load(&sc[7], __ATOMIC_RELAXED, __HIP_MEMORY_SCOPE_AGENT);
            float Sp  = __hip_atomic_load(&sc[4], __ATOMIC_RELAXED, __HIP_MEMORY_SCOPE_AGENT);
            float TLs = __hip_atomic_load(&sc[5], __ATOMIC_RELAXED, __HIP_MEMORY_SCOPE_AGENT);
            const float M = NFF * (NFF - 1.f);
            float Wo  = W - Sp;          // off-diagonal sum of way
            float SGP = P - sg;
            float SGN = Q - sg;
            float TP = tps * (1.f / NFF);
            float o0 = Sp / NFF + Wo / M - LB;
            float o1 = Wo / M + TLs / M - LB;
            float o2 = SGP / M, o3 = SGN / M;
            out[0] = o0;
            out[1] = o1;
            out[2] = o2;
            out[3] = o3;
            out[4] = (TP + 1.f - o3) * 0.5f;
            out[5] = TP;
            out[6] = TP / (TP + o3);
            out[7] = LB;
            out[8] = -o0 + 2.0f;
        }
    }
}

extern "C" void kernel_launch(void* const* d_in, const int* in_sizes, int n_in,
                              void* d_out, int out_size, void* d_ws, size_t ws_size,
                              hipStream_t stream)
{
    const float* X = (const float*)d_in[0];  // z_x (j / columns of logits)
    const float* Y = (const float*)d_in[1];  // z_y (i / rows of logits)
    float* out = (float*)d_out;

    char* ws = (char*)d_ws;
    __hip_bfloat16* Yb = (__hip_bfloat16*)(ws);
    __hip_bfloat16* Xb = (__hip_bfloat16*)(ws + (1 << 20));
    float* yn  = (float*)(ws + (2 << 20));
    float* xn  = yn + N;
    float* pos = xn + N;
    float* g4  = pos + N;          // 4*N per-row raw e-moments
    float* sc  = g4 + 4 * N;       // 16 scalars
    int*   syncv = (int*)(sc + 16);

    k_prep<<<512, 256, 0, stream>>>(X, Y, Xb, Yb, xn, yn, g4, sc, syncv);
    k_main<<<dim3(N / TILE, N / TILE), 256, 0, stream>>>(Yb, Xb, yn, xn, pos, g4);
    k_post<<<16, 256, 0, stream>>>(pos, g4, sc, syncv, out);
}